// Round 13
// baseline (1913.262 us; speedup 1.0000x reference)
//
#include <hip/hip_runtime.h>

typedef unsigned short u16;
typedef unsigned int u32;
typedef __attribute__((ext_vector_type(8))) short short8;
typedef __attribute__((ext_vector_type(4))) float f32x4;

#define N_NODES 10000
#define N_EDGES 100000
#define C_CH 64
#define S_SPH 16
#define NB_R 8
#define HID_D 64
#define NE_EL 10
#define G_GR 64
#define L_LAY 2
#define N_HEADS 1
#define RCUT 5.0f
#define INV_AVG (1.0f/16.0f)

__device__ __forceinline__ u16 f2bf(float f) {
  u32 u = __float_as_uint(f);
  u32 r = (u + 0x7FFFu + ((u >> 16) & 1u)) >> 16;
  return (u16)r;
}

__device__ __forceinline__ float bf2f(u16 v) {
  return __uint_as_float(((u32)v) << 16);
}

__global__ void k_init0(float* __restrict__ out, int* __restrict__ deg, int* __restrict__ bins) {
  int i = blockIdx.x * 256 + threadIdx.x;
  if (i < G_GR) out[i] = 0.0f;
  if (i < 64) bins[i] = 0;
  if (i < N_NODES) deg[i] = 0;
}

__global__ void k_node_init(const float* __restrict__ attrs, const float* __restrict__ ae,
                            const int* __restrict__ batch, const int* __restrict__ head,
                            int* __restrict__ species, float* __restrict__ out) {
  int n = blockIdx.x * 256 + threadIdx.x;
  if (n >= N_NODES) return;
  int sp = 0;
#pragma unroll
  for (int e = 0; e < NE_EL; ++e)
    if (attrs[n * NE_EL + e] > 0.5f) sp = e;
  species[n] = sp;
  int b = batch[n];
  int h = head[b];
  atomicAdd(&out[b], ae[h * NE_EL + sp]);
}

__global__ void k_embed(const int* __restrict__ species, const float* __restrict__ Wemb,
                        float* __restrict__ feats, u16* __restrict__ featsB) {
  int idx = blockIdx.x * 256 + threadIdx.x;
  if (idx >= N_NODES * C_CH) return;
  float v = Wemb[species[idx >> 6] * C_CH + (idx & 63)];
  feats[idx] = v;
  featsB[idx] = f2bf(v);
}

__global__ void k_hist(const int* __restrict__ ei, int* __restrict__ deg) {
  int e = blockIdx.x * 256 + threadIdx.x;
  if (e >= N_EDGES) return;
  atomicAdd(&deg[ei[N_EDGES + e]], 1);
}

__global__ void __launch_bounds__(1024) k_scan(const int* __restrict__ deg,
                                               int* __restrict__ rowptr,
                                               int* __restrict__ woff) {
  __shared__ int wsum[16];
  __shared__ int carry_s;
  int tid = threadIdx.x;
  int lane = tid & 63, w = tid >> 6;
  if (tid == 0) carry_s = 0;
  __syncthreads();
  for (int base = 0; base < N_NODES; base += 1024) {
    int i = base + tid;
    int v = (i < N_NODES) ? deg[i] : 0;
    int orig = v;
#pragma unroll
    for (int off = 1; off < 64; off <<= 1) {
      int n = __shfl_up(v, off, 64);
      if (lane >= off) v += n;
    }
    if (lane == 63) wsum[w] = v;
    __syncthreads();
    if (w == 0 && lane < 16) {
      int x = wsum[lane];
#pragma unroll
      for (int off = 1; off < 16; off <<= 1) {
        int n = __shfl_up(x, off, 16);
        if (lane >= off) x += n;
      }
      wsum[lane] = x;
    }
    __syncthreads();
    int waveoff = (w > 0) ? wsum[w - 1] : 0;
    int carry = carry_s;
    int excl = carry + waveoff + v - orig;
    if (i < N_NODES) {
      rowptr[i] = excl;
      woff[i] = excl;
    }
    int tot = wsum[15];
    __syncthreads();
    if (tid == 0) carry_s = carry + tot;
    __syncthreads();
  }
  if (tid == 0) rowptr[N_NODES] = carry_s;
}

__global__ void k_degbin(const int* __restrict__ deg, int* __restrict__ bins) {
  int n = blockIdx.x * 256 + threadIdx.x;
  if (n >= N_NODES) return;
  int d = min(deg[n], 63);
  atomicAdd(&bins[63 - d], 1);
}

__global__ void __launch_bounds__(64) k_degscan(const int* __restrict__ bins,
                                                int* __restrict__ binoff) {
  int lane = threadIdx.x;
  int v = bins[lane];
  int orig = v;
#pragma unroll
  for (int off = 1; off < 64; off <<= 1) {
    int t = __shfl_up(v, off, 64);
    if (lane >= off) v += t;
  }
  binoff[lane] = v - orig;
}

__global__ void k_degscatter(const int* __restrict__ deg, int* __restrict__ binoff,
                             int* __restrict__ nodeOrder) {
  int n = blockIdx.x * 256 + threadIdx.x;
  if (n >= N_NODES) return;
  int d = min(deg[n], 63);
  int pos = atomicAdd(&binoff[63 - d], 1);
  nodeOrder[pos] = n;
}

__global__ void k_permute(const int* __restrict__ ei, int* __restrict__ woff,
                          int* __restrict__ rank, int* __restrict__ sndp) {
  int e = blockIdx.x * 256 + threadIdx.x;
  if (e >= N_EDGES) return;
  int rdst = ei[N_EDGES + e];
  int pos = atomicAdd(&woff[rdst], 1);
  rank[e] = pos;
  sndp[pos] = ei[e];
}

__global__ void k_geom(const float* __restrict__ pos, const float* __restrict__ shifts,
                       const int* __restrict__ ei, const int* __restrict__ rank,
                       float* __restrict__ Yp, float* __restrict__ radp) {
  int e = blockIdx.x * 256 + threadIdx.x;
  if (e >= N_EDGES) return;
  int s = ei[e], r = ei[N_EDGES + e];
  float dx = pos[r * 3 + 0] - pos[s * 3 + 0] + shifts[e * 3 + 0];
  float dy = pos[r * 3 + 1] - pos[s * 3 + 1] + shifts[e * 3 + 1];
  float dz = pos[r * 3 + 2] - pos[s * 3 + 2] + shifts[e * 3 + 2];
  float rr = sqrtf(dx * dx + dy * dy + dz * dz);
  rr = fmaxf(rr, 1e-12f);
  float inv = 1.0f / rr;
  float x = dx * inv, y = dy * inv, z = dz * inv;
  float xx = x * x, yy = y * y, zz = z * z;
  const float s3 = 1.73205080757f, s5 = 2.2360679775f, s15 = 3.87298334621f;
  const float c1 = 2.09165006634f, c2 = 10.2469507659f, c3 = 1.62018517461f;
  const float c4 = 1.32287565553f, c5 = 5.12347538298f;
  int rk = rank[e];
  float4* Yo = (float4*)(Yp + (size_t)rk * 16);
  Yo[0] = make_float4(1.0f, s3 * x, s3 * y, s3 * z);
  Yo[1] = make_float4(s15 * x * y, s15 * y * z, 0.5f * s5 * (3.0f * zz - 1.0f), s15 * x * z);
  Yo[2] = make_float4(0.5f * s15 * (xx - yy), c1 * y * (3.0f * xx - yy), c2 * x * y * z,
                      c3 * y * (5.0f * zz - 1.0f));
  Yo[3] = make_float4(c4 * z * (5.0f * zz - 3.0f), c3 * x * (5.0f * zz - 1.0f),
                      c5 * z * (xx - yy), c1 * x * (xx - 3.0f * yy));
  float t = rr * (1.0f / RCUT);
  float t2 = t * t;
  float t6 = t2 * t2 * t2;
  float fcut = 1.0f - 28.0f * t6 + 48.0f * t6 * t - 21.0f * t6 * t2;
  if (rr >= RCUT) fcut = 0.0f;
  float pref = 0.63245553203f * inv * fcut;
  float arg = 3.14159265359f * rr * (1.0f / RCUT);
  float sa, ca;
  __sincosf(arg, &sa, &ca);
  float twoc = 2.0f * ca;
  float sprev = 0.0f, scur = sa;
  float rv[8];
#pragma unroll
  for (int n = 0; n < 8; ++n) {
    rv[n] = pref * scur;
    float snext = twoc * scur - sprev;
    sprev = scur;
    scur = snext;
  }
  float4* Ro = (float4*)(radp + (size_t)rk * 8);
  Ro[0] = make_float4(rv[0], rv[1], rv[2], rv[3]);
  Ro[1] = make_float4(rv[4], rv[5], rv[6], rv[7]);
}

__global__ void k_prep(const float* __restrict__ w3, const float* __restrict__ w2,
                       const float* __restrict__ wmix, const float* __restrict__ wup,
                       const float* __restrict__ wskip, u16* __restrict__ w3t,
                       u16* __restrict__ w2t, u16* __restrict__ wmixf,
                       u16* __restrict__ wupf, float* __restrict__ wskt) {
  int idx = blockIdx.x * 256 + threadIdx.x;
  if (idx < L_LAY * 65536) {
    int l = idx >> 16;
    int r = idx & 65535;
    int k = r & 63;
    int c = (r >> 6) & 63;
    int s = r >> 12;
    w3t[idx] = f2bf(w3[(l * 64 + k) * 1024 + c * 16 + s]);
  } else if (idx < L_LAY * 65536 + L_LAY * 4096) {
    int i = idx - L_LAY * 65536;
    int l = i >> 12;
    int r = i & 4095;
    int t = r >> 6;
    int j = r & 63;
    w2t[l * 4096 + t * 64 + j] = f2bf(w2[(l * 64 + j) * 64 + t]);
  } else if (idx < L_LAY * 65536 + 2 * L_LAY * 4096) {
    int i = idx - L_LAY * 65536 - L_LAY * 4096;
    int l = i >> 12;
    int r = i & 4095;
    int j = r & 7;
    int col = (r >> 3) & 15;
    int kg = (r >> 7) & 3;
    int hf = (r >> 9) & 1;
    int dc = (r >> 10) & 3;
    int c = hf * 32 + kg * 8 + j;
    int d = dc * 16 + col;
    wmixf[l * 4096 + r] = f2bf(wmix[(l * 64 + c) * 64 + d]);
  } else if (idx < L_LAY * 65536 + 3 * L_LAY * 4096) {
    int i = idx - L_LAY * 65536 - 2 * L_LAY * 4096;
    int l = i >> 12;
    int r = i & 4095;
    int j = r & 7;
    int col = (r >> 3) & 15;
    int kg = (r >> 7) & 3;
    int hf = (r >> 9) & 1;
    int dc = (r >> 10) & 3;
    int c = hf * 32 + kg * 8 + j;
    int d = dc * 16 + col;
    wupf[l * 4096 + r] = f2bf(wup[(l * 64 + c) * 64 + d] * INV_AVG);
  } else if (idx < L_LAY * 65536 + 3 * L_LAY * 4096 + L_LAY * 40960) {
    int i = idx - (L_LAY * 65536 + 3 * L_LAY * 4096);
    int l = (i >= 40960) ? 1 : 0;
    int r = i - l * 40960;
    int e = r >> 12;
    int rem = r & 4095;
    int c = rem >> 6;
    int d = rem & 63;
    wskt[(size_t)l * 40960 + e * 4096 + c * 64 + d] =
        wskip[(size_t)l * 40960 + c * 640 + e * 64 + d];
  }
}

// Solo-wave mega kernel: 1 wave = 1 node; ALL LDS traffic wave-private;
// ZERO per-chunk __syncthreads (only one initial barrier for w1s).
// Per 16-slot chunk: edge MLP -> h2 (private, swizzled), up-MFMA -> upL
// (validity-masked), Y -> Yts; then 4cg x 16s MFMA accumulation into
// Areg[4][2][8]; final cross-kg shfl reduce; mix/poly/skip/Wout/energy.
__global__ void __launch_bounds__(256) k_gather_solo(
    const float* __restrict__ radp, const float* __restrict__ Yp,
    const int* __restrict__ sndp, const u16* __restrict__ featsB,
    const u16* __restrict__ W3T, const u16* __restrict__ w2T,
    const u16* __restrict__ WupF, const float* __restrict__ w1,
    const int* __restrict__ rowptr, const int* __restrict__ nodeOrder,
    const u16* __restrict__ WmixF, const float* __restrict__ featsOld,
    float* __restrict__ featsNew, u16* __restrict__ featsBN,
    const float* __restrict__ WskT, const float* __restrict__ Wc,
    const float* __restrict__ WoutG, const float* __restrict__ Wro,
    const int* __restrict__ species, const int* __restrict__ batch,
    const int* __restrict__ headArr, float* __restrict__ out) {
  __shared__ __align__(16) u16 h2s[4][1024];     // 8 KB (16 rows x 64, swizzled)
  __shared__ __align__(16) float Yts[4][16][20]; // 5 KB (80B pitch, 16B-aligned)
  __shared__ __align__(16) u16 upL[4][16][72];   // 9 KB
  __shared__ __align__(16) u16 Asub[4][16][72];  // 9 KB; aliased as h1 scratch
  __shared__ float w1s[NB_R * HID_D];            // 2 KB
  __shared__ float qs[4][64];
  __shared__ float fsub[4][64];
  int tid = threadIdx.x;
  int wv = tid >> 6, lane = tid & 63;
  int row = lane & 15, kg = lane >> 4;
  int er = row, jg = kg;
  int col = row;
  int nodeW = nodeOrder[blockIdx.x * 4 + wv];
  int rpA = rowptr[nodeW];
  int degW = rowptr[nodeW + 1] - rpA;
  for (int i = tid; i < NB_R * HID_D; i += 256) w1s[i] = w1[i];
  fsub[wv][lane] = featsOld[(size_t)nodeW * 64 + lane];
  __syncthreads();  // the ONLY barrier: w1s ready

  int chunks = max((degW + 15) >> 4, 1);
  u32* h1b = (u32*)&Asub[wv][0][0];        // 2 KB scratch, live only during chunks
  const u32* h2w = (const u32*)&h2s[wv][0];

  float Areg[4][2][8];
#pragma unroll
  for (int cg = 0; cg < 4; ++cg)
#pragma unroll
    for (int hf = 0; hf < 2; ++hf)
#pragma unroll
      for (int ss = 0; ss < 8; ++ss) Areg[cg][hf][ss] = 0.f;

#pragma unroll 1
  for (int c0 = 0; c0 < chunks; ++c0) {
    int slotBase = c0 * 16;
    int eW = min(rpA + slotBase + er, N_EDGES - 1);
    // ---- edge MLP (wave-private) ----
    float4 ra = *(const float4*)(radp + (size_t)eW * 8);
    float4 rb = *(const float4*)(radp + (size_t)eW * 8 + 4);
    float rv[8] = {ra.x, ra.y, ra.z, ra.w, rb.x, rb.y, rb.z, rb.w};
#pragma unroll
    for (int jj = 0; jj < 16; jj += 2) {
      float p0 = 0.f, p1 = 0.f;
#pragma unroll
      for (int k = 0; k < 8; ++k) {
        p0 += rv[k] * w1s[k * 64 + jg * 16 + jj];
        p1 += rv[k] * w1s[k * 64 + jg * 16 + jj + 1];
      }
      p0 = p0 / (1.f + __expf(-p0));
      p1 = p1 / (1.f + __expf(-p1));
      u32 packed = (u32)f2bf(p0) | ((u32)f2bf(p1) << 16);
      int d = jg * 8 + (jj >> 1);
      h1b[er * 32 + (d ^ ((er & 7) << 2))] = packed;
    }
    short8 ea0 = *(const short8*)&h1b[er * 32 + ((jg * 4) ^ ((er & 7) << 2))];
    short8 ea1 = *(const short8*)&h1b[er * 32 + ((16 + jg * 4) ^ ((er & 7) << 2))];
#pragma unroll
    for (int ch = 0; ch < 4; ++ch) {
      const u16* wp = w2T + (ch * 16 + er) * 64 + jg * 8;
      short8 b0 = *(const short8*)wp;
      short8 b1 = *(const short8*)(wp + 32);
      f32x4 acc = {0.f, 0.f, 0.f, 0.f};
      acc = __builtin_amdgcn_mfma_f32_16x16x32_bf16(ea0, b0, acc, 0, 0, 0);
      acc = __builtin_amdgcn_mfma_f32_16x16x32_bf16(ea1, b1, acc, 0, 0, 0);
#pragma unroll
      for (int rr = 0; rr < 4; ++rr) {
        float v = acc[rr];
        v = v / (1.f + __expf(-v));
        int R = jg * 4 + rr;
        int c = ch * 16 + er;
        int g = (c >> 3) ^ ((R ^ (R >> 3)) & 7);
        h2s[wv][R * 64 + g * 8 + (er & 7)] = f2bf(v);
      }
    }
    // ---- up tile (validity-masked) ----
    int snd = sndp[eW];
    short8 fa0 = *(const short8*)(featsB + (size_t)snd * 64 + jg * 8);
    short8 fa1 = *(const short8*)(featsB + (size_t)snd * 64 + 32 + jg * 8);
#pragma unroll
    for (int cgi = 0; cgi < 4; ++cgi) {
      short8 wf0 = *(const short8*)(WupF + cgi * 1024 + jg * 128 + er * 8);
      short8 wf1 = *(const short8*)(WupF + cgi * 1024 + 512 + jg * 128 + er * 8);
      f32x4 acc = {0.f, 0.f, 0.f, 0.f};
      acc = __builtin_amdgcn_mfma_f32_16x16x32_bf16(fa0, wf0, acc, 0, 0, 0);
      acc = __builtin_amdgcn_mfma_f32_16x16x32_bf16(fa1, wf1, acc, 0, 0, 0);
#pragma unroll
      for (int r = 0; r < 4; ++r) {
        int m = jg * 4 + r;
        u16 uv = (slotBase + m < degW) ? f2bf(acc[r]) : (u16)0;
        upL[wv][m][cgi * 16 + er] = uv;
      }
    }
    // ---- Y tile ----
    float4 y = *(const float4*)(Yp + (size_t)eW * 16 + jg * 4);
    Yts[wv][jg * 4 + 0][er] = y.x;
    Yts[wv][jg * 4 + 1][er] = y.y;
    Yts[wv][jg * 4 + 2][er] = y.z;
    Yts[wv][jg * 4 + 3][er] = y.w;
    // ---- compute (no barrier: wave-private LDS; compiler inserts lgkmcnt) ----
    int swz = ((row ^ (row >> 3)) & 7) << 2;
    short8 a0 = *(const short8*)(h2w + row * 32 + ((kg * 4) ^ swz));
    short8 a1 = *(const short8*)(h2w + row * 32 + ((16 + kg * 4) ^ swz));
#pragma unroll
    for (int cg = 0; cg < 4; ++cg) {
      float u0 = bf2f(upL[wv][kg * 4 + 0][cg * 16 + col]);
      float u1 = bf2f(upL[wv][kg * 4 + 1][cg * 16 + col]);
      float u2 = bf2f(upL[wv][kg * 4 + 2][cg * 16 + col]);
      float u3 = bf2f(upL[wv][kg * 4 + 3][cg * 16 + col]);
#pragma unroll
      for (int hf = 0; hf < 2; ++hf) {
        short8 B0[8], B1[8];
#pragma unroll
        for (int ss = 0; ss < 8; ++ss) {
          int s = hf * 8 + ss;
          const u16* wp = W3T + (((s * 64 + cg * 16 + col) << 6) + kg * 8);
          B0[ss] = *(const short8*)wp;
          B1[ss] = *(const short8*)(wp + 32);
        }
#pragma unroll
        for (int ss = 0; ss < 8; ++ss) {
          f32x4 acc = {0.f, 0.f, 0.f, 0.f};
          acc = __builtin_amdgcn_mfma_f32_16x16x32_bf16(a0, B0[ss], acc, 0, 0, 0);
          acc = __builtin_amdgcn_mfma_f32_16x16x32_bf16(a1, B1[ss], acc, 0, 0, 0);
          float4 yv = *(const float4*)&Yts[wv][hf * 8 + ss][kg * 4];
          Areg[cg][hf][ss] += acc[0] * yv.x * u0 + acc[1] * yv.y * u1 + acc[2] * yv.z * u2 +
                              acc[3] * yv.w * u3;
        }
      }
    }
  }
  // ---- cross-kg reduce (slots kg*4+r summed over kg groups) ----
#pragma unroll
  for (int cg = 0; cg < 4; ++cg)
#pragma unroll
    for (int hf = 0; hf < 2; ++hf)
#pragma unroll
      for (int ss = 0; ss < 8; ++ss) {
        float v = Areg[cg][hf][ss];
        v += __shfl_xor(v, 16, 64);
        v += __shfl_xor(v, 32, 64);
        Areg[cg][hf][ss] = v;
      }
  // ---- write A (lane kg writes cg==kg slice; h1b scratch now dead) ----
#pragma unroll
  for (int cgi = 0; cgi < 4; ++cgi) {
    if (cgi == kg) {
#pragma unroll
      for (int hf = 0; hf < 2; ++hf)
#pragma unroll
        for (int ss = 0; ss < 8; ++ss)
          Asub[wv][hf * 8 + ss][cgi * 16 + col] = f2bf(Areg[cgi][hf][ss]);
    }
  }
  // ---- phase 2: mix + poly (wave-private) ----
  int sp = species[nodeW];
  short8 a0m = *(const short8*)&Asub[wv][row][kg * 8];
  short8 a1m = *(const short8*)&Asub[wv][row][32 + kg * 8];
#pragma unroll
  for (int dc = 0; dc < 4; ++dc) {
    short8 wf0 = *(const short8*)(WmixF + (size_t)(dc * 1024 + 0 * 512 + kg * 128 + row * 8));
    short8 wf1 = *(const short8*)(WmixF + (size_t)(dc * 1024 + 1 * 512 + kg * 128 + row * 8));
    f32x4 acc = {0.f, 0.f, 0.f, 0.f};
    acc = __builtin_amdgcn_mfma_f32_16x16x32_bf16(a0m, wf0, acc, 0, 0, 0);
    acc = __builtin_amdgcn_mfma_f32_16x16x32_bf16(a1m, wf1, acc, 0, 0, 0);
    float psq = acc[0] * acc[0] + acc[1] * acc[1] + acc[2] * acc[2] + acc[3] * acc[3];
    psq += __shfl_xor(psq, 16, 64);
    psq += __shfl_xor(psq, 32, 64);
    float p1 = __shfl(acc[0], lane & 15, 64);
    float p3 = psq * p1;
    int d = dc * 16 + row;
    float qv = Wc[(sp * 3 + 0) * 64 + d] * p1 + Wc[(sp * 3 + 1) * 64 + d] * psq +
               Wc[(sp * 3 + 2) * 64 + d] * p3;
    if (kg == 0) qs[wv][d] = qv;
  }
  // ---- phase 3: skip + Wout + energy (wave-private) ----
  int t = lane;
  const float* wsk = WskT + (size_t)sp * 4096;
  float sc = 0.f;
#pragma unroll 8
  for (int c = 0; c < 64; ++c) sc += fsub[wv][c] * wsk[c * 64 + t];
  float v = sc;
#pragma unroll 8
  for (int d = 0; d < 64; ++d) v += qs[wv][d] * WoutG[d * 64 + t];
  featsNew[(size_t)nodeW * 64 + t] = v;
  featsBN[(size_t)nodeW * 64 + t] = f2bf(v);
  int b = batch[nodeW];
  float en = v * Wro[t * N_HEADS + headArr[b]];
#pragma unroll
  for (int off = 32; off; off >>= 1) en += __shfl_down(en, off, 64);
  if (lane == 0) atomicAdd(&out[b], en);
}

extern "C" void kernel_launch(void* const* d_in, const int* in_sizes, int n_in,
                              void* d_out, int out_size, void* d_ws, size_t ws_size,
                              hipStream_t stream) {
  const float* pos = (const float*)d_in[0];
  const float* attrs = (const float*)d_in[1];
  const float* shifts = (const float*)d_in[2];
  const float* ae = (const float*)d_in[3];
  const float* Wemb = (const float*)d_in[4];
  const float* Wup = (const float*)d_in[5];
  const float* w1 = (const float*)d_in[6];
  const float* w2 = (const float*)d_in[7];
  const float* w3 = (const float*)d_in[8];
  const float* Wmix = (const float*)d_in[9];
  const float* Wskip = (const float*)d_in[10];
  const float* Wc = (const float*)d_in[11];
  const float* Wout = (const float*)d_in[12];
  const float* Wro = (const float*)d_in[13];
  const int* ei = (const int*)d_in[14];
  const int* batch = (const int*)d_in[15];
  const int* head = (const int*)d_in[16];
  float* out = (float*)d_out;

  char* p = (char*)d_ws;
  float* Yp = (float*)p;     p += (size_t)N_EDGES * 16 * 4;
  float* radp = (float*)p;   p += (size_t)N_EDGES * 8 * 4;
  float* fA = (float*)p;     p += (size_t)N_NODES * 64 * 4;
  float* fB = (float*)p;     p += (size_t)N_NODES * 64 * 4;
  u16* fBa = (u16*)p;        p += (size_t)N_NODES * 64 * 2;
  u16* fBb = (u16*)p;        p += (size_t)N_NODES * 64 * 2;
  u16* W3T = (u16*)p;        p += (size_t)L_LAY * 65536 * 2;
  u16* w2T = (u16*)p;        p += (size_t)L_LAY * 4096 * 2;
  u16* WmixF = (u16*)p;      p += (size_t)L_LAY * 4096 * 2;
  u16* WupF = (u16*)p;       p += (size_t)L_LAY * 4096 * 2;
  float* WskT = (float*)p;   p += (size_t)L_LAY * 40960 * 4;
  int* species = (int*)p;    p += (size_t)N_NODES * 4;
  int* deg = (int*)p;        p += (size_t)N_NODES * 4;
  int* rowptr = (int*)p;     p += (size_t)(N_NODES + 4) * 4;
  int* woff = (int*)p;       p += (size_t)N_NODES * 4;
  int* rank = (int*)p;       p += (size_t)N_EDGES * 4;
  int* sndp = (int*)p;       p += (size_t)N_EDGES * 4;
  int* bins = (int*)p;       p += 64 * 4;
  int* binoff = (int*)p;     p += 64 * 4;
  int* nodeOrder = (int*)p;  p += (size_t)N_NODES * 4;
  if ((size_t)(p - (char*)d_ws) > ws_size) return;

  k_init0<<<(N_NODES + 255) / 256, 256, 0, stream>>>(out, deg, bins);
  k_node_init<<<(N_NODES + 255) / 256, 256, 0, stream>>>(attrs, ae, batch, head, species, out);
  k_embed<<<(N_NODES * C_CH + 255) / 256, 256, 0, stream>>>(species, Wemb, fA, fBa);
  k_hist<<<(N_EDGES + 255) / 256, 256, 0, stream>>>(ei, deg);
  k_scan<<<1, 1024, 0, stream>>>(deg, rowptr, woff);
  k_degbin<<<(N_NODES + 255) / 256, 256, 0, stream>>>(deg, bins);
  k_degscan<<<1, 64, 0, stream>>>(bins, binoff);
  k_degscatter<<<(N_NODES + 255) / 256, 256, 0, stream>>>(deg, binoff, nodeOrder);
  k_permute<<<(N_EDGES + 255) / 256, 256, 0, stream>>>(ei, woff, rank, sndp);
  k_geom<<<(N_EDGES + 255) / 256, 256, 0, stream>>>(pos, shifts, ei, rank, Yp, radp);
  int prepTot = L_LAY * 65536 + 3 * L_LAY * 4096 + L_LAY * 40960;
  k_prep<<<(prepTot + 255) / 256, 256, 0, stream>>>(w3, w2, Wmix, Wup, Wskip, W3T, w2T, WmixF,
                                                    WupF, WskT);

  const float* fOld = fA;
  float* fNew = fB;
  const u16* fBOld = fBa;
  u16* fBNew = fBb;
  for (int l = 0; l < L_LAY; ++l) {
    k_gather_solo<<<N_NODES / 4, 256, 0, stream>>>(
        radp, Yp, sndp, fBOld, W3T + l * 65536, w2T + l * 4096, WupF + l * 4096,
        w1 + l * NB_R * HID_D, rowptr, nodeOrder, WmixF + l * 4096, fOld, fNew, fBNew,
        WskT + (size_t)l * 40960, Wc + l * NE_EL * 3 * C_CH, Wout + l * C_CH * C_CH,
        Wro + l * C_CH * N_HEADS, species, batch, head, out);
    const float* tf = fNew; fNew = (float*)fOld; fOld = tf;
    const u16* tb = fBNew; fBNew = (u16*)fBOld; fBOld = tb;
  }
}

// Round 14
// 525.669 us; speedup vs baseline: 3.6397x; 3.6397x over previous
//
#include <hip/hip_runtime.h>

typedef unsigned short u16;
typedef unsigned int u32;
typedef __attribute__((ext_vector_type(8))) short short8;
typedef __attribute__((ext_vector_type(4))) float f32x4;

#define N_NODES 10000
#define N_EDGES 100000
#define C_CH 64
#define S_SPH 16
#define NB_R 8
#define HID_D 64
#define NE_EL 10
#define G_GR 64
#define L_LAY 2
#define N_HEADS 1
#define RCUT 5.0f
#define INV_AVG (1.0f/16.0f)

__device__ __forceinline__ u16 f2bf(float f) {
  u32 u = __float_as_uint(f);
  u32 r = (u + 0x7FFFu + ((u >> 16) & 1u)) >> 16;
  return (u16)r;
}

__device__ __forceinline__ float bf2f(u16 v) {
  return __uint_as_float(((u32)v) << 16);
}

__global__ void k_init0(float* __restrict__ out, int* __restrict__ deg, int* __restrict__ bins) {
  int i = blockIdx.x * 256 + threadIdx.x;
  if (i < G_GR) out[i] = 0.0f;
  if (i < 64) bins[i] = 0;
  if (i < N_NODES) deg[i] = 0;
}

__global__ void k_node_init(const float* __restrict__ attrs, const float* __restrict__ ae,
                            const int* __restrict__ batch, const int* __restrict__ head,
                            int* __restrict__ species, float* __restrict__ out) {
  int n = blockIdx.x * 256 + threadIdx.x;
  if (n >= N_NODES) return;
  int sp = 0;
#pragma unroll
  for (int e = 0; e < NE_EL; ++e)
    if (attrs[n * NE_EL + e] > 0.5f) sp = e;
  species[n] = sp;
  int b = batch[n];
  int h = head[b];
  atomicAdd(&out[b], ae[h * NE_EL + sp]);
}

__global__ void k_embed(const int* __restrict__ species, const float* __restrict__ Wemb,
                        float* __restrict__ feats, u16* __restrict__ featsB) {
  int idx = blockIdx.x * 256 + threadIdx.x;
  if (idx >= N_NODES * C_CH) return;
  float v = Wemb[species[idx >> 6] * C_CH + (idx & 63)];
  feats[idx] = v;
  featsB[idx] = f2bf(v);
}

__global__ void k_hist(const int* __restrict__ ei, int* __restrict__ deg) {
  int e = blockIdx.x * 256 + threadIdx.x;
  if (e >= N_EDGES) return;
  atomicAdd(&deg[ei[N_EDGES + e]], 1);
}

__global__ void __launch_bounds__(1024) k_scan(const int* __restrict__ deg,
                                               int* __restrict__ rowptr,
                                               int* __restrict__ woff) {
  __shared__ int wsum[16];
  __shared__ int carry_s;
  int tid = threadIdx.x;
  int lane = tid & 63, w = tid >> 6;
  if (tid == 0) carry_s = 0;
  __syncthreads();
  for (int base = 0; base < N_NODES; base += 1024) {
    int i = base + tid;
    int v = (i < N_NODES) ? deg[i] : 0;
    int orig = v;
#pragma unroll
    for (int off = 1; off < 64; off <<= 1) {
      int n = __shfl_up(v, off, 64);
      if (lane >= off) v += n;
    }
    if (lane == 63) wsum[w] = v;
    __syncthreads();
    if (w == 0 && lane < 16) {
      int x = wsum[lane];
#pragma unroll
      for (int off = 1; off < 16; off <<= 1) {
        int n = __shfl_up(x, off, 16);
        if (lane >= off) x += n;
      }
      wsum[lane] = x;
    }
    __syncthreads();
    int waveoff = (w > 0) ? wsum[w - 1] : 0;
    int carry = carry_s;
    int excl = carry + waveoff + v - orig;
    if (i < N_NODES) {
      rowptr[i] = excl;
      woff[i] = excl;
    }
    int tot = wsum[15];
    __syncthreads();
    if (tid == 0) carry_s = carry + tot;
    __syncthreads();
  }
  if (tid == 0) rowptr[N_NODES] = carry_s;
}

__global__ void k_degbin(const int* __restrict__ deg, int* __restrict__ bins) {
  int n = blockIdx.x * 256 + threadIdx.x;
  if (n >= N_NODES) return;
  int d = min(deg[n], 63);
  atomicAdd(&bins[63 - d], 1);
}

__global__ void __launch_bounds__(64) k_degscan(const int* __restrict__ bins,
                                                int* __restrict__ binoff) {
  int lane = threadIdx.x;
  int v = bins[lane];
  int orig = v;
#pragma unroll
  for (int off = 1; off < 64; off <<= 1) {
    int t = __shfl_up(v, off, 64);
    if (lane >= off) v += t;
  }
  binoff[lane] = v - orig;
}

__global__ void k_degscatter(const int* __restrict__ deg, int* __restrict__ binoff,
                             int* __restrict__ nodeOrder) {
  int n = blockIdx.x * 256 + threadIdx.x;
  if (n >= N_NODES) return;
  int d = min(deg[n], 63);
  int pos = atomicAdd(&binoff[63 - d], 1);
  nodeOrder[pos] = n;
}

__global__ void k_permute(const int* __restrict__ ei, int* __restrict__ woff,
                          int* __restrict__ rank, int* __restrict__ sndp) {
  int e = blockIdx.x * 256 + threadIdx.x;
  if (e >= N_EDGES) return;
  int rdst = ei[N_EDGES + e];
  int pos = atomicAdd(&woff[rdst], 1);
  rank[e] = pos;
  sndp[pos] = ei[e];
}

__global__ void k_geom(const float* __restrict__ pos, const float* __restrict__ shifts,
                       const int* __restrict__ ei, const int* __restrict__ rank,
                       float* __restrict__ Yp, float* __restrict__ radp) {
  int e = blockIdx.x * 256 + threadIdx.x;
  if (e >= N_EDGES) return;
  int s = ei[e], r = ei[N_EDGES + e];
  float dx = pos[r * 3 + 0] - pos[s * 3 + 0] + shifts[e * 3 + 0];
  float dy = pos[r * 3 + 1] - pos[s * 3 + 1] + shifts[e * 3 + 1];
  float dz = pos[r * 3 + 2] - pos[s * 3 + 2] + shifts[e * 3 + 2];
  float rr = sqrtf(dx * dx + dy * dy + dz * dz);
  rr = fmaxf(rr, 1e-12f);
  float inv = 1.0f / rr;
  float x = dx * inv, y = dy * inv, z = dz * inv;
  float xx = x * x, yy = y * y, zz = z * z;
  const float s3 = 1.73205080757f, s5 = 2.2360679775f, s15 = 3.87298334621f;
  const float c1 = 2.09165006634f, c2 = 10.2469507659f, c3 = 1.62018517461f;
  const float c4 = 1.32287565553f, c5 = 5.12347538298f;
  int rk = rank[e];
  float4* Yo = (float4*)(Yp + (size_t)rk * 16);
  Yo[0] = make_float4(1.0f, s3 * x, s3 * y, s3 * z);
  Yo[1] = make_float4(s15 * x * y, s15 * y * z, 0.5f * s5 * (3.0f * zz - 1.0f), s15 * x * z);
  Yo[2] = make_float4(0.5f * s15 * (xx - yy), c1 * y * (3.0f * xx - yy), c2 * x * y * z,
                      c3 * y * (5.0f * zz - 1.0f));
  Yo[3] = make_float4(c4 * z * (5.0f * zz - 3.0f), c3 * x * (5.0f * zz - 1.0f),
                      c5 * z * (xx - yy), c1 * x * (xx - 3.0f * yy));
  float t = rr * (1.0f / RCUT);
  float t2 = t * t;
  float t6 = t2 * t2 * t2;
  float fcut = 1.0f - 28.0f * t6 + 48.0f * t6 * t - 21.0f * t6 * t2;
  if (rr >= RCUT) fcut = 0.0f;
  float pref = 0.63245553203f * inv * fcut;
  float arg = 3.14159265359f * rr * (1.0f / RCUT);
  float sa, ca;
  __sincosf(arg, &sa, &ca);
  float twoc = 2.0f * ca;
  float sprev = 0.0f, scur = sa;
  float rv[8];
#pragma unroll
  for (int n = 0; n < 8; ++n) {
    rv[n] = pref * scur;
    float snext = twoc * scur - sprev;
    sprev = scur;
    scur = snext;
  }
  float4* Ro = (float4*)(radp + (size_t)rk * 8);
  Ro[0] = make_float4(rv[0], rv[1], rv[2], rv[3]);
  Ro[1] = make_float4(rv[4], rv[5], rv[6], rv[7]);
}

__global__ void k_prep(const float* __restrict__ w3, const float* __restrict__ w2,
                       const float* __restrict__ wmix, const float* __restrict__ wup,
                       const float* __restrict__ wskip, u16* __restrict__ w3t,
                       u16* __restrict__ w2t, u16* __restrict__ wmixf,
                       u16* __restrict__ wupf, float* __restrict__ wskt) {
  int idx = blockIdx.x * 256 + threadIdx.x;
  if (idx < L_LAY * 65536) {
    int l = idx >> 16;
    int r = idx & 65535;
    int k = r & 63;
    int c = (r >> 6) & 63;
    int s = r >> 12;
    w3t[idx] = f2bf(w3[(l * 64 + k) * 1024 + c * 16 + s]);
  } else if (idx < L_LAY * 65536 + L_LAY * 4096) {
    int i = idx - L_LAY * 65536;
    int l = i >> 12;
    int r = i & 4095;
    int t = r >> 6;
    int j = r & 63;
    w2t[l * 4096 + t * 64 + j] = f2bf(w2[(l * 64 + j) * 64 + t]);
  } else if (idx < L_LAY * 65536 + 2 * L_LAY * 4096) {
    int i = idx - L_LAY * 65536 - L_LAY * 4096;
    int l = i >> 12;
    int r = i & 4095;
    int j = r & 7;
    int col = (r >> 3) & 15;
    int kg = (r >> 7) & 3;
    int hf = (r >> 9) & 1;
    int dc = (r >> 10) & 3;
    int c = hf * 32 + kg * 8 + j;
    int d = dc * 16 + col;
    wmixf[l * 4096 + r] = f2bf(wmix[(l * 64 + c) * 64 + d]);
  } else if (idx < L_LAY * 65536 + 3 * L_LAY * 4096) {
    int i = idx - L_LAY * 65536 - 2 * L_LAY * 4096;
    int l = i >> 12;
    int r = i & 4095;
    int j = r & 7;
    int col = (r >> 3) & 15;
    int kg = (r >> 7) & 3;
    int hf = (r >> 9) & 1;
    int dc = (r >> 10) & 3;
    int c = hf * 32 + kg * 8 + j;
    int d = dc * 16 + col;
    wupf[l * 4096 + r] = f2bf(wup[(l * 64 + c) * 64 + d] * INV_AVG);
  } else if (idx < L_LAY * 65536 + 3 * L_LAY * 4096 + L_LAY * 40960) {
    int i = idx - (L_LAY * 65536 + 3 * L_LAY * 4096);
    int l = (i >= 40960) ? 1 : 0;
    int r = i - l * 40960;
    int e = r >> 12;
    int rem = r & 4095;
    int c = rem >> 6;
    int d = rem & 63;
    wskt[(size_t)l * 40960 + e * 4096 + c * 64 + d] =
        wskip[(size_t)l * 40960 + c * 640 + e * 64 + d];
  }
}

// Mega-fused layer kernel (R11 structure) + T14 async-STAGE split:
// chunk c+1's global loads (radp, sndp->featsB, Yp) are issued into registers
// right after the post-staging barrier, landing during chunk c's MFMA compute.
__global__ void __launch_bounds__(256) k_gather_mega(
    const float* __restrict__ radp, const float* __restrict__ Yp,
    const int* __restrict__ sndp, const u16* __restrict__ featsB,
    const u16* __restrict__ W3T, const u16* __restrict__ w2T,
    const u16* __restrict__ WupF, const float* __restrict__ w1,
    const int* __restrict__ rowptr, const int* __restrict__ nodeOrder,
    const u16* __restrict__ WmixF, const float* __restrict__ featsOld,
    float* __restrict__ featsNew, u16* __restrict__ featsBN,
    const float* __restrict__ WskT, const float* __restrict__ Wc,
    const float* __restrict__ WoutG, const float* __restrict__ Wro,
    const int* __restrict__ species, const int* __restrict__ batch,
    const int* __restrict__ headArr, float* __restrict__ out) {
  __shared__ __align__(16) u16 h2s[64 * 64];
  __shared__ __align__(16) float Yts[16][68];
  __shared__ __align__(16) u16 upL[64 * 72];
  __shared__ __align__(16) u16 Asub[4][16][72];
  __shared__ float w1s[NB_R * HID_D];
  __shared__ float qs[4][64];
  __shared__ float fsub[4][64];
  __shared__ int rpsA[4], rpsB[4];
  int tid = threadIdx.x;
  int wv = tid >> 6, lane = tid & 63;
  int row = lane & 15, kg = lane >> 4;
  int er = row, jg = kg;
  int col = row;
  int cgc = wv * 16 + col;
  int nb = blockIdx.x * 4;
  int nodeW = nodeOrder[nb + wv];
  if (tid < 4) {
    int n = nodeOrder[nb + tid];
    rpsA[tid] = rowptr[n];
    rpsB[tid] = rowptr[n + 1];
  }
  for (int i = tid; i < NB_R * HID_D; i += 256) w1s[i] = w1[i];
  fsub[wv][lane] = featsOld[(size_t)nodeW * 64 + lane];
  __syncthreads();
  int dmax = 0;
#pragma unroll
  for (int i = 0; i < 4; ++i) dmax = max(dmax, rpsB[i] - rpsA[i]);
  int rmax = max((dmax + 3) >> 2, 1);
  int rpsAw = rpsA[wv];
  int degW = rpsB[wv] - rpsAw;

  u32* h1b = (u32*)&Asub[0][0][0] + wv * 512;
  const u32* h2sr = (const u32*)h2s;

  float Areg[2][8];
#pragma unroll
  for (int hf = 0; hf < 2; ++hf)
#pragma unroll
    for (int ss = 0; ss < 8; ++ss) Areg[hf][ss] = 0.f;

  // ---- register-resident staged inputs for the CURRENT chunk ----
  float rvR[8];
  short8 fa0R, fa1R;
  float4 yqR;

#define LOADCH(R0)                                                       \
  {                                                                      \
    int eW_ = min(rpsAw + (R0) * 4 + er, N_EDGES - 1);                   \
    float4 ra_ = *(const float4*)(radp + (size_t)eW_ * 8);               \
    float4 rb_ = *(const float4*)(radp + (size_t)eW_ * 8 + 4);           \
    rvR[0] = ra_.x; rvR[1] = ra_.y; rvR[2] = ra_.z; rvR[3] = ra_.w;      \
    rvR[4] = rb_.x; rvR[5] = rb_.y; rvR[6] = rb_.z; rvR[7] = rb_.w;      \
    int snd_ = sndp[eW_];                                                \
    fa0R = *(const short8*)(featsB + (size_t)snd_ * 64 + jg * 8);        \
    fa1R = *(const short8*)(featsB + (size_t)snd_ * 64 + 32 + jg * 8);   \
    yqR = *(const float4*)(Yp + (size_t)eW_ * 16 + jg * 4);              \
  }

  LOADCH(0);  // prologue

#pragma unroll 1
  for (int r0 = 0; r0 < rmax; r0 += 4) {
    int CH = min(4, rmax - r0);
    int slotBase = r0 * 4;
    __syncthreads();  // previous chunk's compute done before LDS overwrite
    // ---- staging from registers: edge MLP -> h2s, up tile -> upL, Y -> Yts ----
#pragma unroll
    for (int jj = 0; jj < 16; jj += 2) {
      float p0 = 0.f, p1 = 0.f;
#pragma unroll
      for (int k = 0; k < 8; ++k) {
        p0 += rvR[k] * w1s[k * 64 + jg * 16 + jj];
        p1 += rvR[k] * w1s[k * 64 + jg * 16 + jj + 1];
      }
      p0 = p0 / (1.f + __expf(-p0));
      p1 = p1 / (1.f + __expf(-p1));
      u32 packed = (u32)f2bf(p0) | ((u32)f2bf(p1) << 16);
      int d = jg * 8 + (jj >> 1);
      h1b[er * 32 + (d ^ ((er & 7) << 2))] = packed;
    }
    short8 ea0 = *(const short8*)&h1b[er * 32 + ((jg * 4) ^ ((er & 7) << 2))];
    short8 ea1 = *(const short8*)&h1b[er * 32 + ((16 + jg * 4) ^ ((er & 7) << 2))];
#pragma unroll
    for (int ch = 0; ch < 4; ++ch) {
      const u16* wp = w2T + (ch * 16 + er) * 64 + jg * 8;
      short8 b0 = *(const short8*)wp;
      short8 b1 = *(const short8*)(wp + 32);
      f32x4 acc = {0.f, 0.f, 0.f, 0.f};
      acc = __builtin_amdgcn_mfma_f32_16x16x32_bf16(ea0, b0, acc, 0, 0, 0);
      acc = __builtin_amdgcn_mfma_f32_16x16x32_bf16(ea1, b1, acc, 0, 0, 0);
#pragma unroll
      for (int rr = 0; rr < 4; ++rr) {
        float v = acc[rr];
        v = v / (1.f + __expf(-v));
        int R = wv * 16 + jg * 4 + rr;
        int c = ch * 16 + er;
        int g = (c >> 3) ^ ((R ^ (R >> 3)) & 7);
        h2s[R * 64 + g * 8 + (er & 7)] = f2bf(v);
      }
    }
#pragma unroll
    for (int cgi = 0; cgi < 4; ++cgi) {
      short8 wf0 = *(const short8*)(WupF + cgi * 1024 + jg * 128 + er * 8);
      short8 wf1 = *(const short8*)(WupF + cgi * 1024 + 512 + jg * 128 + er * 8);
      f32x4 acc = {0.f, 0.f, 0.f, 0.f};
      acc = __builtin_amdgcn_mfma_f32_16x16x32_bf16(fa0R, wf0, acc, 0, 0, 0);
      acc = __builtin_amdgcn_mfma_f32_16x16x32_bf16(fa1R, wf1, acc, 0, 0, 0);
#pragma unroll
      for (int r = 0; r < 4; ++r) {
        int m = jg * 4 + r;
        u16 uv = (slotBase + m < degW) ? f2bf(acc[r]) : (u16)0;
        upL[(wv * 16 + m) * 72 + cgi * 16 + er] = uv;
      }
    }
    Yts[jg * 4 + 0][wv * 16 + er] = yqR.x;
    Yts[jg * 4 + 1][wv * 16 + er] = yqR.y;
    Yts[jg * 4 + 2][wv * 16 + er] = yqR.z;
    Yts[jg * 4 + 3][wv * 16 + er] = yqR.w;
    __syncthreads();
    // ---- T14: issue NEXT chunk's global loads (land during compute) ----
    if (r0 + 4 < rmax) LOADCH(r0 + 4);
    // ---- compute phase (cg = wv), all operands in LDS / L2-hot W3T ----
#pragma unroll 1
    for (int hf = 0; hf < 2; ++hf) {
      short8 B0[8], B1[8];
#pragma unroll
      for (int ss = 0; ss < 8; ++ss) {
        int s = hf * 8 + ss;
        const u16* wp = W3T + (((s * 64 + wv * 16 + col) << 6) + kg * 8);
        B0[ss] = *(const short8*)wp;
        B1[ss] = *(const short8*)(wp + 32);
      }
#pragma unroll 1
      for (int rl = 0; rl < CH; ++rl) {
        int srow = (row >> 2) * 16 + rl * 4 + (row & 3);
        int swz = (((srow ^ (srow >> 3)) & 7) << 2);
        short8 a0 = *(const short8*)(h2sr + srow * 32 + ((kg * 4) ^ swz));
        short8 a1 = *(const short8*)(h2sr + srow * 32 + ((16 + kg * 4) ^ swz));
        float u0 = bf2f(upL[(kg * 16 + rl * 4 + 0) * 72 + cgc]);
        float u1 = bf2f(upL[(kg * 16 + rl * 4 + 1) * 72 + cgc]);
        float u2 = bf2f(upL[(kg * 16 + rl * 4 + 2) * 72 + cgc]);
        float u3 = bf2f(upL[(kg * 16 + rl * 4 + 3) * 72 + cgc]);
        int ybase = kg * 16 + rl * 4;
#pragma unroll
        for (int ss = 0; ss < 8; ++ss) {
          f32x4 acc = {0.f, 0.f, 0.f, 0.f};
          acc = __builtin_amdgcn_mfma_f32_16x16x32_bf16(a0, B0[ss], acc, 0, 0, 0);
          acc = __builtin_amdgcn_mfma_f32_16x16x32_bf16(a1, B1[ss], acc, 0, 0, 0);
          float4 yv = *(const float4*)&Yts[hf * 8 + ss][ybase];
          Areg[hf][ss] += acc[0] * yv.x * u0 + acc[1] * yv.y * u1 + acc[2] * yv.z * u2 +
                          acc[3] * yv.w * u3;
        }
      }
    }
  }
#undef LOADCH
#pragma unroll
  for (int hf = 0; hf < 2; ++hf)
#pragma unroll
    for (int ss = 0; ss < 8; ++ss) Asub[kg][hf * 8 + ss][wv * 16 + col] = f2bf(Areg[hf][ss]);
  __syncthreads();

  // ---- phase 2: mix + poly ----
  int sp = species[nodeW];
  short8 a0m = *(const short8*)&Asub[wv][row][kg * 8];
  short8 a1m = *(const short8*)&Asub[wv][row][32 + kg * 8];
#pragma unroll
  for (int dc = 0; dc < 4; ++dc) {
    short8 wf0 = *(const short8*)(WmixF + (size_t)(dc * 1024 + 0 * 512 + kg * 128 + row * 8));
    short8 wf1 = *(const short8*)(WmixF + (size_t)(dc * 1024 + 1 * 512 + kg * 128 + row * 8));
    f32x4 acc = {0.f, 0.f, 0.f, 0.f};
    acc = __builtin_amdgcn_mfma_f32_16x16x32_bf16(a0m, wf0, acc, 0, 0, 0);
    acc = __builtin_amdgcn_mfma_f32_16x16x32_bf16(a1m, wf1, acc, 0, 0, 0);
    float psq = acc[0] * acc[0] + acc[1] * acc[1] + acc[2] * acc[2] + acc[3] * acc[3];
    psq += __shfl_xor(psq, 16, 64);
    psq += __shfl_xor(psq, 32, 64);
    float p1 = __shfl(acc[0], lane & 15, 64);
    float p3 = psq * p1;
    int d = dc * 16 + row;
    float qv = Wc[(sp * 3 + 0) * 64 + d] * p1 + Wc[(sp * 3 + 1) * 64 + d] * psq +
               Wc[(sp * 3 + 2) * 64 + d] * p3;
    if (kg == 0) qs[wv][d] = qv;
  }

  // ---- phase 3: skip + Wout + energy ----
  int t = lane;
  const float* wsk = WskT + (size_t)sp * 4096;
  float sc = 0.f;
#pragma unroll 8
  for (int c = 0; c < 64; ++c) sc += fsub[wv][c] * wsk[c * 64 + t];
  float v = sc;
#pragma unroll 8
  for (int d = 0; d < 64; ++d) v += qs[wv][d] * WoutG[d * 64 + t];
  featsNew[(size_t)nodeW * 64 + t] = v;
  featsBN[(size_t)nodeW * 64 + t] = f2bf(v);
  int b = batch[nodeW];
  float en = v * Wro[t * N_HEADS + headArr[b]];
#pragma unroll
  for (int off = 32; off; off >>= 1) en += __shfl_down(en, off, 64);
  if (lane == 0) atomicAdd(&out[b], en);
}

extern "C" void kernel_launch(void* const* d_in, const int* in_sizes, int n_in,
                              void* d_out, int out_size, void* d_ws, size_t ws_size,
                              hipStream_t stream) {
  const float* pos = (const float*)d_in[0];
  const float* attrs = (const float*)d_in[1];
  const float* shifts = (const float*)d_in[2];
  const float* ae = (const float*)d_in[3];
  const float* Wemb = (const float*)d_in[4];
  const float* Wup = (const float*)d_in[5];
  const float* w1 = (const float*)d_in[6];
  const float* w2 = (const float*)d_in[7];
  const float* w3 = (const float*)d_in[8];
  const float* Wmix = (const float*)d_in[9];
  const float* Wskip = (const float*)d_in[10];
  const float* Wc = (const float*)d_in[11];
  const float* Wout = (const float*)d_in[12];
  const float* Wro = (const float*)d_in[13];
  const int* ei = (const int*)d_in[14];
  const int* batch = (const int*)d_in[15];
  const int* head = (const int*)d_in[16];
  float* out = (float*)d_out;

  char* p = (char*)d_ws;
  float* Yp = (float*)p;     p += (size_t)N_EDGES * 16 * 4;
  float* radp = (float*)p;   p += (size_t)N_EDGES * 8 * 4;
  float* fA = (float*)p;     p += (size_t)N_NODES * 64 * 4;
  float* fB = (float*)p;     p += (size_t)N_NODES * 64 * 4;
  u16* fBa = (u16*)p;        p += (size_t)N_NODES * 64 * 2;
  u16* fBb = (u16*)p;        p += (size_t)N_NODES * 64 * 2;
  u16* W3T = (u16*)p;        p += (size_t)L_LAY * 65536 * 2;
  u16* w2T = (u16*)p;        p += (size_t)L_LAY * 4096 * 2;
  u16* WmixF = (u16*)p;      p += (size_t)L_LAY * 4096 * 2;
  u16* WupF = (u16*)p;       p += (size_t)L_LAY * 4096 * 2;
  float* WskT = (float*)p;   p += (size_t)L_LAY * 40960 * 4;
  int* species = (int*)p;    p += (size_t)N_NODES * 4;
  int* deg = (int*)p;        p += (size_t)N_NODES * 4;
  int* rowptr = (int*)p;     p += (size_t)(N_NODES + 4) * 4;
  int* woff = (int*)p;       p += (size_t)N_NODES * 4;
  int* rank = (int*)p;       p += (size_t)N_EDGES * 4;
  int* sndp = (int*)p;       p += (size_t)N_EDGES * 4;
  int* bins = (int*)p;       p += 64 * 4;
  int* binoff = (int*)p;     p += 64 * 4;
  int* nodeOrder = (int*)p;  p += (size_t)N_NODES * 4;
  if ((size_t)(p - (char*)d_ws) > ws_size) return;

  k_init0<<<(N_NODES + 255) / 256, 256, 0, stream>>>(out, deg, bins);
  k_node_init<<<(N_NODES + 255) / 256, 256, 0, stream>>>(attrs, ae, batch, head, species, out);
  k_embed<<<(N_NODES * C_CH + 255) / 256, 256, 0, stream>>>(species, Wemb, fA, fBa);
  k_hist<<<(N_EDGES + 255) / 256, 256, 0, stream>>>(ei, deg);
  k_scan<<<1, 1024, 0, stream>>>(deg, rowptr, woff);
  k_degbin<<<(N_NODES + 255) / 256, 256, 0, stream>>>(deg, bins);
  k_degscan<<<1, 64, 0, stream>>>(bins, binoff);
  k_degscatter<<<(N_NODES + 255) / 256, 256, 0, stream>>>(deg, binoff, nodeOrder);
  k_permute<<<(N_EDGES + 255) / 256, 256, 0, stream>>>(ei, woff, rank, sndp);
  k_geom<<<(N_EDGES + 255) / 256, 256, 0, stream>>>(pos, shifts, ei, rank, Yp, radp);
  int prepTot = L_LAY * 65536 + 3 * L_LAY * 4096 + L_LAY * 40960;
  k_prep<<<(prepTot + 255) / 256, 256, 0, stream>>>(w3, w2, Wmix, Wup, Wskip, W3T, w2T, WmixF,
                                                    WupF, WskT);

  const float* fOld = fA;
  float* fNew = fB;
  const u16* fBOld = fBa;
  u16* fBNew = fBb;
  for (int l = 0; l < L_LAY; ++l) {
    k_gather_mega<<<N_NODES / 4, 256, 0, stream>>>(
        radp, Yp, sndp, fBOld, W3T + l * 65536, w2T + l * 4096, WupF + l * 4096,
        w1 + l * NB_R * HID_D, rowptr, nodeOrder, WmixF + l * 4096, fOld, fNew, fBNew,
        WskT + (size_t)l * 40960, Wc + l * NE_EL * 3 * C_CH, Wout + l * C_CH * C_CH,
        Wro + l * C_CH * N_HEADS, species, batch, head, out);
    const float* tf = fNew; fNew = (float*)fOld; fOld = tf;
    const u16* tb = fBNew; fBNew = (u16*)fBOld; fBOld = tb;
  }
}

// Round 15
// 436.983 us; speedup vs baseline: 4.3783x; 1.2029x over previous
//
#include <hip/hip_runtime.h>

typedef unsigned short u16;
typedef unsigned int u32;
typedef __attribute__((ext_vector_type(8))) short short8;
typedef __attribute__((ext_vector_type(4))) float f32x4;

#define N_NODES 10000
#define N_EDGES 100000
#define C_CH 64
#define S_SPH 16
#define NB_R 8
#define HID_D 64
#define NE_EL 10
#define G_GR 64
#define L_LAY 2
#define N_HEADS 1
#define RCUT 5.0f
#define INV_AVG (1.0f/16.0f)

__device__ __forceinline__ u16 f2bf(float f) {
  u32 u = __float_as_uint(f);
  u32 r = (u + 0x7FFFu + ((u >> 16) & 1u)) >> 16;
  return (u16)r;
}

__device__ __forceinline__ float bf2f(u16 v) {
  return __uint_as_float(((u32)v) << 16);
}

__global__ void k_init0(float* __restrict__ out, int* __restrict__ deg, int* __restrict__ bins) {
  int i = blockIdx.x * 256 + threadIdx.x;
  if (i < G_GR) out[i] = 0.0f;
  if (i < 64) bins[i] = 0;
  if (i < N_NODES) deg[i] = 0;
}

__global__ void k_node_init(const float* __restrict__ attrs, const float* __restrict__ ae,
                            const int* __restrict__ batch, const int* __restrict__ head,
                            int* __restrict__ species, float* __restrict__ out) {
  int n = blockIdx.x * 256 + threadIdx.x;
  if (n >= N_NODES) return;
  int sp = 0;
#pragma unroll
  for (int e = 0; e < NE_EL; ++e)
    if (attrs[n * NE_EL + e] > 0.5f) sp = e;
  species[n] = sp;
  int b = batch[n];
  int h = head[b];
  atomicAdd(&out[b], ae[h * NE_EL + sp]);
}

__global__ void k_embed(const int* __restrict__ species, const float* __restrict__ Wemb,
                        float* __restrict__ feats, u16* __restrict__ featsB) {
  int idx = blockIdx.x * 256 + threadIdx.x;
  if (idx >= N_NODES * C_CH) return;
  float v = Wemb[species[idx >> 6] * C_CH + (idx & 63)];
  feats[idx] = v;
  featsB[idx] = f2bf(v);
}

__global__ void k_hist(const int* __restrict__ ei, int* __restrict__ deg) {
  int e = blockIdx.x * 256 + threadIdx.x;
  if (e >= N_EDGES) return;
  atomicAdd(&deg[ei[N_EDGES + e]], 1);
}

__global__ void __launch_bounds__(1024) k_scan(const int* __restrict__ deg,
                                               int* __restrict__ rowptr,
                                               int* __restrict__ woff) {
  __shared__ int wsum[16];
  __shared__ int carry_s;
  int tid = threadIdx.x;
  int lane = tid & 63, w = tid >> 6;
  if (tid == 0) carry_s = 0;
  __syncthreads();
  for (int base = 0; base < N_NODES; base += 1024) {
    int i = base + tid;
    int v = (i < N_NODES) ? deg[i] : 0;
    int orig = v;
#pragma unroll
    for (int off = 1; off < 64; off <<= 1) {
      int n = __shfl_up(v, off, 64);
      if (lane >= off) v += n;
    }
    if (lane == 63) wsum[w] = v;
    __syncthreads();
    if (w == 0 && lane < 16) {
      int x = wsum[lane];
#pragma unroll
      for (int off = 1; off < 16; off <<= 1) {
        int n = __shfl_up(x, off, 16);
        if (lane >= off) x += n;
      }
      wsum[lane] = x;
    }
    __syncthreads();
    int waveoff = (w > 0) ? wsum[w - 1] : 0;
    int carry = carry_s;
    int excl = carry + waveoff + v - orig;
    if (i < N_NODES) {
      rowptr[i] = excl;
      woff[i] = excl;
    }
    int tot = wsum[15];
    __syncthreads();
    if (tid == 0) carry_s = carry + tot;
    __syncthreads();
  }
  if (tid == 0) rowptr[N_NODES] = carry_s;
}

__global__ void k_degbin(const int* __restrict__ deg, int* __restrict__ bins) {
  int n = blockIdx.x * 256 + threadIdx.x;
  if (n >= N_NODES) return;
  int d = min(deg[n], 63);
  atomicAdd(&bins[63 - d], 1);
}

__global__ void __launch_bounds__(64) k_degscan(const int* __restrict__ bins,
                                                int* __restrict__ binoff) {
  int lane = threadIdx.x;
  int v = bins[lane];
  int orig = v;
#pragma unroll
  for (int off = 1; off < 64; off <<= 1) {
    int t = __shfl_up(v, off, 64);
    if (lane >= off) v += t;
  }
  binoff[lane] = v - orig;
}

__global__ void k_degscatter(const int* __restrict__ deg, int* __restrict__ binoff,
                             int* __restrict__ nodeOrder) {
  int n = blockIdx.x * 256 + threadIdx.x;
  if (n >= N_NODES) return;
  int d = min(deg[n], 63);
  int pos = atomicAdd(&binoff[63 - d], 1);
  nodeOrder[pos] = n;
}

__global__ void k_permute(const int* __restrict__ ei, int* __restrict__ woff,
                          int* __restrict__ rank, int* __restrict__ sndp) {
  int e = blockIdx.x * 256 + threadIdx.x;
  if (e >= N_EDGES) return;
  int rdst = ei[N_EDGES + e];
  int pos = atomicAdd(&woff[rdst], 1);
  rank[e] = pos;
  sndp[pos] = ei[e];
}

__global__ void k_geom(const float* __restrict__ pos, const float* __restrict__ shifts,
                       const int* __restrict__ ei, const int* __restrict__ rank,
                       float* __restrict__ Yp, float* __restrict__ radp) {
  int e = blockIdx.x * 256 + threadIdx.x;
  if (e >= N_EDGES) return;
  int s = ei[e], r = ei[N_EDGES + e];
  float dx = pos[r * 3 + 0] - pos[s * 3 + 0] + shifts[e * 3 + 0];
  float dy = pos[r * 3 + 1] - pos[s * 3 + 1] + shifts[e * 3 + 1];
  float dz = pos[r * 3 + 2] - pos[s * 3 + 2] + shifts[e * 3 + 2];
  float rr = sqrtf(dx * dx + dy * dy + dz * dz);
  rr = fmaxf(rr, 1e-12f);
  float inv = 1.0f / rr;
  float x = dx * inv, y = dy * inv, z = dz * inv;
  float xx = x * x, yy = y * y, zz = z * z;
  const float s3 = 1.73205080757f, s5 = 2.2360679775f, s15 = 3.87298334621f;
  const float c1 = 2.09165006634f, c2 = 10.2469507659f, c3 = 1.62018517461f;
  const float c4 = 1.32287565553f, c5 = 5.12347538298f;
  int rk = rank[e];
  float4* Yo = (float4*)(Yp + (size_t)rk * 16);
  Yo[0] = make_float4(1.0f, s3 * x, s3 * y, s3 * z);
  Yo[1] = make_float4(s15 * x * y, s15 * y * z, 0.5f * s5 * (3.0f * zz - 1.0f), s15 * x * z);
  Yo[2] = make_float4(0.5f * s15 * (xx - yy), c1 * y * (3.0f * xx - yy), c2 * x * y * z,
                      c3 * y * (5.0f * zz - 1.0f));
  Yo[3] = make_float4(c4 * z * (5.0f * zz - 3.0f), c3 * x * (5.0f * zz - 1.0f),
                      c5 * z * (xx - yy), c1 * x * (xx - 3.0f * yy));
  float t = rr * (1.0f / RCUT);
  float t2 = t * t;
  float t6 = t2 * t2 * t2;
  float fcut = 1.0f - 28.0f * t6 + 48.0f * t6 * t - 21.0f * t6 * t2;
  if (rr >= RCUT) fcut = 0.0f;
  float pref = 0.63245553203f * inv * fcut;
  float arg = 3.14159265359f * rr * (1.0f / RCUT);
  float sa, ca;
  __sincosf(arg, &sa, &ca);
  float twoc = 2.0f * ca;
  float sprev = 0.0f, scur = sa;
  float rv[8];
#pragma unroll
  for (int n = 0; n < 8; ++n) {
    rv[n] = pref * scur;
    float snext = twoc * scur - sprev;
    sprev = scur;
    scur = snext;
  }
  float4* Ro = (float4*)(radp + (size_t)rk * 8);
  Ro[0] = make_float4(rv[0], rv[1], rv[2], rv[3]);
  Ro[1] = make_float4(rv[4], rv[5], rv[6], rv[7]);
}

__global__ void k_prep(const float* __restrict__ w3, const float* __restrict__ w2,
                       const float* __restrict__ wmix, const float* __restrict__ wup,
                       const float* __restrict__ wskip, u16* __restrict__ w3t,
                       u16* __restrict__ w2t, u16* __restrict__ wmixf,
                       u16* __restrict__ wupf, float* __restrict__ wskt) {
  int idx = blockIdx.x * 256 + threadIdx.x;
  if (idx < L_LAY * 65536) {
    int l = idx >> 16;
    int r = idx & 65535;
    int k = r & 63;
    int c = (r >> 6) & 63;
    int s = r >> 12;
    w3t[idx] = f2bf(w3[(l * 64 + k) * 1024 + c * 16 + s]);
  } else if (idx < L_LAY * 65536 + L_LAY * 4096) {
    int i = idx - L_LAY * 65536;
    int l = i >> 12;
    int r = i & 4095;
    int t = r >> 6;
    int j = r & 63;
    w2t[l * 4096 + t * 64 + j] = f2bf(w2[(l * 64 + j) * 64 + t]);
  } else if (idx < L_LAY * 65536 + 2 * L_LAY * 4096) {
    int i = idx - L_LAY * 65536 - L_LAY * 4096;
    int l = i >> 12;
    int r = i & 4095;
    int j = r & 7;
    int col = (r >> 3) & 15;
    int kg = (r >> 7) & 3;
    int hf = (r >> 9) & 1;
    int dc = (r >> 10) & 3;
    int c = hf * 32 + kg * 8 + j;
    int d = dc * 16 + col;
    wmixf[l * 4096 + r] = f2bf(wmix[(l * 64 + c) * 64 + d]);
  } else if (idx < L_LAY * 65536 + 3 * L_LAY * 4096) {
    int i = idx - L_LAY * 65536 - 2 * L_LAY * 4096;
    int l = i >> 12;
    int r = i & 4095;
    int j = r & 7;
    int col = (r >> 3) & 15;
    int kg = (r >> 7) & 3;
    int hf = (r >> 9) & 1;
    int dc = (r >> 10) & 3;
    int c = hf * 32 + kg * 8 + j;
    int d = dc * 16 + col;
    wupf[l * 4096 + r] = f2bf(wup[(l * 64 + c) * 64 + d] * INV_AVG);
  } else if (idx < L_LAY * 65536 + 3 * L_LAY * 4096 + L_LAY * 40960) {
    int i = idx - (L_LAY * 65536 + 3 * L_LAY * 4096);
    int l = (i >= 40960) ? 1 : 0;
    int r = i - l * 40960;
    int e = r >> 12;
    int rem = r & 4095;
    int c = rem >> 6;
    int d = rem & 63;
    wskt[(size_t)l * 40960 + e * 4096 + c * 64 + d] =
        wskip[(size_t)l * 40960 + c * 640 + e * 64 + d];
  }
}

// Mega-fused layer kernel (R11 best-known configuration, verbatim):
// per chunk, wave wv computes its node's h2 tile (edge MLP, MFMA), up tile
// (featsB bf16 @ WupF, MFMA), and Y tile into LDS; then the compute phase
// runs entirely from LDS (+L2-hot W3T). Validity enforced solely via upL=0.
__global__ void __launch_bounds__(256) k_gather_mega(
    const float* __restrict__ radp, const float* __restrict__ Yp,
    const int* __restrict__ sndp, const u16* __restrict__ featsB,
    const u16* __restrict__ W3T, const u16* __restrict__ w2T,
    const u16* __restrict__ WupF, const float* __restrict__ w1,
    const int* __restrict__ rowptr, const int* __restrict__ nodeOrder,
    const u16* __restrict__ WmixF, const float* __restrict__ featsOld,
    float* __restrict__ featsNew, u16* __restrict__ featsBN,
    const float* __restrict__ WskT, const float* __restrict__ Wc,
    const float* __restrict__ WoutG, const float* __restrict__ Wro,
    const int* __restrict__ species, const int* __restrict__ batch,
    const int* __restrict__ headArr, float* __restrict__ out) {
  __shared__ __align__(16) u16 h2s[64 * 64];
  __shared__ __align__(16) float Yts[16][68];
  __shared__ __align__(16) u16 upL[64 * 72];
  __shared__ __align__(16) u16 Asub[4][16][72];
  __shared__ float w1s[NB_R * HID_D];
  __shared__ float qs[4][64];
  __shared__ float fsub[4][64];
  __shared__ int rpsA[4], rpsB[4];
  int tid = threadIdx.x;
  int wv = tid >> 6, lane = tid & 63;
  int row = lane & 15, kg = lane >> 4;
  int er = row, jg = kg;
  int col = row;
  int cgc = wv * 16 + col;
  int nb = blockIdx.x * 4;
  int nodeW = nodeOrder[nb + wv];
  if (tid < 4) {
    int n = nodeOrder[nb + tid];
    rpsA[tid] = rowptr[n];
    rpsB[tid] = rowptr[n + 1];
  }
  for (int i = tid; i < NB_R * HID_D; i += 256) w1s[i] = w1[i];
  fsub[wv][lane] = featsOld[(size_t)nodeW * 64 + lane];
  __syncthreads();
  int dmax = 0;
#pragma unroll
  for (int i = 0; i < 4; ++i) dmax = max(dmax, rpsB[i] - rpsA[i]);
  int rmax = max((dmax + 3) >> 2, 1);
  int rpsAw = rpsA[wv];
  int degW = rpsB[wv] - rpsAw;

  u32* h1b = (u32*)&Asub[0][0][0] + wv * 512;
  const u32* h2sr = (const u32*)h2s;

  float Areg[2][8];
#pragma unroll
  for (int hf = 0; hf < 2; ++hf)
#pragma unroll
    for (int ss = 0; ss < 8; ++ss) Areg[hf][ss] = 0.f;

#pragma unroll 1
  for (int r0 = 0; r0 < rmax; r0 += 4) {
    int CH = min(4, rmax - r0);
    int slotBase = r0 * 4;
    __syncthreads();
    // ---- staging: edge MLP -> h2s, up tile -> upL, Y -> Yts ----
    int eW = min(rpsAw + slotBase + er, N_EDGES - 1);
    float4 ra = *(const float4*)(radp + (size_t)eW * 8);
    float4 rb = *(const float4*)(radp + (size_t)eW * 8 + 4);
    float rv[8] = {ra.x, ra.y, ra.z, ra.w, rb.x, rb.y, rb.z, rb.w};
#pragma unroll
    for (int jj = 0; jj < 16; jj += 2) {
      float p0 = 0.f, p1 = 0.f;
#pragma unroll
      for (int k = 0; k < 8; ++k) {
        p0 += rv[k] * w1s[k * 64 + jg * 16 + jj];
        p1 += rv[k] * w1s[k * 64 + jg * 16 + jj + 1];
      }
      p0 = p0 / (1.f + __expf(-p0));
      p1 = p1 / (1.f + __expf(-p1));
      u32 packed = (u32)f2bf(p0) | ((u32)f2bf(p1) << 16);
      int d = jg * 8 + (jj >> 1);
      h1b[er * 32 + (d ^ ((er & 7) << 2))] = packed;
    }
    short8 ea0 = *(const short8*)&h1b[er * 32 + ((jg * 4) ^ ((er & 7) << 2))];
    short8 ea1 = *(const short8*)&h1b[er * 32 + ((16 + jg * 4) ^ ((er & 7) << 2))];
#pragma unroll
    for (int ch = 0; ch < 4; ++ch) {
      const u16* wp = w2T + (ch * 16 + er) * 64 + jg * 8;
      short8 b0 = *(const short8*)wp;
      short8 b1 = *(const short8*)(wp + 32);
      f32x4 acc = {0.f, 0.f, 0.f, 0.f};
      acc = __builtin_amdgcn_mfma_f32_16x16x32_bf16(ea0, b0, acc, 0, 0, 0);
      acc = __builtin_amdgcn_mfma_f32_16x16x32_bf16(ea1, b1, acc, 0, 0, 0);
#pragma unroll
      for (int rr = 0; rr < 4; ++rr) {
        float v = acc[rr];
        v = v / (1.f + __expf(-v));
        int R = wv * 16 + jg * 4 + rr;
        int c = ch * 16 + er;
        int g = (c >> 3) ^ ((R ^ (R >> 3)) & 7);
        h2s[R * 64 + g * 8 + (er & 7)] = f2bf(v);
      }
    }
    int snd = sndp[eW];
    short8 fa0 = *(const short8*)(featsB + (size_t)snd * 64 + jg * 8);
    short8 fa1 = *(const short8*)(featsB + (size_t)snd * 64 + 32 + jg * 8);
#pragma unroll
    for (int cgi = 0; cgi < 4; ++cgi) {
      short8 wf0 = *(const short8*)(WupF + cgi * 1024 + jg * 128 + er * 8);
      short8 wf1 = *(const short8*)(WupF + cgi * 1024 + 512 + jg * 128 + er * 8);
      f32x4 acc = {0.f, 0.f, 0.f, 0.f};
      acc = __builtin_amdgcn_mfma_f32_16x16x32_bf16(fa0, wf0, acc, 0, 0, 0);
      acc = __builtin_amdgcn_mfma_f32_16x16x32_bf16(fa1, wf1, acc, 0, 0, 0);
#pragma unroll
      for (int r = 0; r < 4; ++r) {
        int m = jg * 4 + r;
        u16 uv = (slotBase + m < degW) ? f2bf(acc[r]) : (u16)0;
        upL[(wv * 16 + m) * 72 + cgi * 16 + er] = uv;
      }
    }
    float4 y = *(const float4*)(Yp + (size_t)eW * 16 + jg * 4);
    Yts[jg * 4 + 0][wv * 16 + er] = y.x;
    Yts[jg * 4 + 1][wv * 16 + er] = y.y;
    Yts[jg * 4 + 2][wv * 16 + er] = y.z;
    Yts[jg * 4 + 3][wv * 16 + er] = y.w;
    __syncthreads();
    // ---- compute phase (cg = wv), all operands in LDS / L2-hot W3T ----
#pragma unroll 1
    for (int hf = 0; hf < 2; ++hf) {
      short8 B0[8], B1[8];
#pragma unroll
      for (int ss = 0; ss < 8; ++ss) {
        int s = hf * 8 + ss;
        const u16* wp = W3T + (((s * 64 + wv * 16 + col) << 6) + kg * 8);
        B0[ss] = *(const short8*)wp;
        B1[ss] = *(const short8*)(wp + 32);
      }
#pragma unroll 1
      for (int rl = 0; rl < CH; ++rl) {
        int srow = (row >> 2) * 16 + rl * 4 + (row & 3);
        int swz = (((srow ^ (srow >> 3)) & 7) << 2);
        short8 a0 = *(const short8*)(h2sr + srow * 32 + ((kg * 4) ^ swz));
        short8 a1 = *(const short8*)(h2sr + srow * 32 + ((16 + kg * 4) ^ swz));
        float u0 = bf2f(upL[(kg * 16 + rl * 4 + 0) * 72 + cgc]);
        float u1 = bf2f(upL[(kg * 16 + rl * 4 + 1) * 72 + cgc]);
        float u2 = bf2f(upL[(kg * 16 + rl * 4 + 2) * 72 + cgc]);
        float u3 = bf2f(upL[(kg * 16 + rl * 4 + 3) * 72 + cgc]);
        int ybase = kg * 16 + rl * 4;
#pragma unroll
        for (int ss = 0; ss < 8; ++ss) {
          f32x4 acc = {0.f, 0.f, 0.f, 0.f};
          acc = __builtin_amdgcn_mfma_f32_16x16x32_bf16(a0, B0[ss], acc, 0, 0, 0);
          acc = __builtin_amdgcn_mfma_f32_16x16x32_bf16(a1, B1[ss], acc, 0, 0, 0);
          float4 yv = *(const float4*)&Yts[hf * 8 + ss][ybase];
          Areg[hf][ss] += acc[0] * yv.x * u0 + acc[1] * yv.y * u1 + acc[2] * yv.z * u2 +
                          acc[3] * yv.w * u3;
        }
      }
    }
  }
#pragma unroll
  for (int hf = 0; hf < 2; ++hf)
#pragma unroll
    for (int ss = 0; ss < 8; ++ss) Asub[kg][hf * 8 + ss][wv * 16 + col] = f2bf(Areg[hf][ss]);
  __syncthreads();

  // ---- phase 2: mix + poly ----
  int sp = species[nodeW];
  short8 a0m = *(const short8*)&Asub[wv][row][kg * 8];
  short8 a1m = *(const short8*)&Asub[wv][row][32 + kg * 8];
#pragma unroll
  for (int dc = 0; dc < 4; ++dc) {
    short8 wf0 = *(const short8*)(WmixF + (size_t)(dc * 1024 + 0 * 512 + kg * 128 + row * 8));
    short8 wf1 = *(const short8*)(WmixF + (size_t)(dc * 1024 + 1 * 512 + kg * 128 + row * 8));
    f32x4 acc = {0.f, 0.f, 0.f, 0.f};
    acc = __builtin_amdgcn_mfma_f32_16x16x32_bf16(a0m, wf0, acc, 0, 0, 0);
    acc = __builtin_amdgcn_mfma_f32_16x16x32_bf16(a1m, wf1, acc, 0, 0, 0);
    float psq = acc[0] * acc[0] + acc[1] * acc[1] + acc[2] * acc[2] + acc[3] * acc[3];
    psq += __shfl_xor(psq, 16, 64);
    psq += __shfl_xor(psq, 32, 64);
    float p1 = __shfl(acc[0], lane & 15, 64);
    float p3 = psq * p1;
    int d = dc * 16 + row;
    float qv = Wc[(sp * 3 + 0) * 64 + d] * p1 + Wc[(sp * 3 + 1) * 64 + d] * psq +
               Wc[(sp * 3 + 2) * 64 + d] * p3;
    if (kg == 0) qs[wv][d] = qv;
  }

  // ---- phase 3: skip + Wout + energy ----
  int t = lane;
  const float* wsk = WskT + (size_t)sp * 4096;
  float sc = 0.f;
#pragma unroll 8
  for (int c = 0; c < 64; ++c) sc += fsub[wv][c] * wsk[c * 64 + t];
  float v = sc;
#pragma unroll 8
  for (int d = 0; d < 64; ++d) v += qs[wv][d] * WoutG[d * 64 + t];
  featsNew[(size_t)nodeW * 64 + t] = v;
  featsBN[(size_t)nodeW * 64 + t] = f2bf(v);
  int b = batch[nodeW];
  float en = v * Wro[t * N_HEADS + headArr[b]];
#pragma unroll
  for (int off = 32; off; off >>= 1) en += __shfl_down(en, off, 64);
  if (lane == 0) atomicAdd(&out[b], en);
}

extern "C" void kernel_launch(void* const* d_in, const int* in_sizes, int n_in,
                              void* d_out, int out_size, void* d_ws, size_t ws_size,
                              hipStream_t stream) {
  const float* pos = (const float*)d_in[0];
  const float* attrs = (const float*)d_in[1];
  const float* shifts = (const float*)d_in[2];
  const float* ae = (const float*)d_in[3];
  const float* Wemb = (const float*)d_in[4];
  const float* Wup = (const float*)d_in[5];
  const float* w1 = (const float*)d_in[6];
  const float* w2 = (const float*)d_in[7];
  const float* w3 = (const float*)d_in[8];
  const float* Wmix = (const float*)d_in[9];
  const float* Wskip = (const float*)d_in[10];
  const float* Wc = (const float*)d_in[11];
  const float* Wout = (const float*)d_in[12];
  const float* Wro = (const float*)d_in[13];
  const int* ei = (const int*)d_in[14];
  const int* batch = (const int*)d_in[15];
  const int* head = (const int*)d_in[16];
  float* out = (float*)d_out;

  char* p = (char*)d_ws;
  float* Yp = (float*)p;     p += (size_t)N_EDGES * 16 * 4;
  float* radp = (float*)p;   p += (size_t)N_EDGES * 8 * 4;
  float* fA = (float*)p;     p += (size_t)N_NODES * 64 * 4;
  float* fB = (float*)p;     p += (size_t)N_NODES * 64 * 4;
  u16* fBa = (u16*)p;        p += (size_t)N_NODES * 64 * 2;
  u16* fBb = (u16*)p;        p += (size_t)N_NODES * 64 * 2;
  u16* W3T = (u16*)p;        p += (size_t)L_LAY * 65536 * 2;
  u16* w2T = (u16*)p;        p += (size_t)L_LAY * 4096 * 2;
  u16* WmixF = (u16*)p;      p += (size_t)L_LAY * 4096 * 2;
  u16* WupF = (u16*)p;       p += (size_t)L_LAY * 4096 * 2;
  float* WskT = (float*)p;   p += (size_t)L_LAY * 40960 * 4;
  int* species = (int*)p;    p += (size_t)N_NODES * 4;
  int* deg = (int*)p;        p += (size_t)N_NODES * 4;
  int* rowptr = (int*)p;     p += (size_t)(N_NODES + 4) * 4;
  int* woff = (int*)p;       p += (size_t)N_NODES * 4;
  int* rank = (int*)p;       p += (size_t)N_EDGES * 4;
  int* sndp = (int*)p;       p += (size_t)N_EDGES * 4;
  int* bins = (int*)p;       p += 64 * 4;
  int* binoff = (int*)p;     p += 64 * 4;
  int* nodeOrder = (int*)p;  p += (size_t)N_NODES * 4;
  if ((size_t)(p - (char*)d_ws) > ws_size) return;

  k_init0<<<(N_NODES + 255) / 256, 256, 0, stream>>>(out, deg, bins);
  k_node_init<<<(N_NODES + 255) / 256, 256, 0, stream>>>(attrs, ae, batch, head, species, out);
  k_embed<<<(N_NODES * C_CH + 255) / 256, 256, 0, stream>>>(species, Wemb, fA, fBa);
  k_hist<<<(N_EDGES + 255) / 256, 256, 0, stream>>>(ei, deg);
  k_scan<<<1, 1024, 0, stream>>>(deg, rowptr, woff);
  k_degbin<<<(N_NODES + 255) / 256, 256, 0, stream>>>(deg, bins);
  k_degscan<<<1, 64, 0, stream>>>(bins, binoff);
  k_degscatter<<<(N_NODES + 255) / 256, 256, 0, stream>>>(deg, binoff, nodeOrder);
  k_permute<<<(N_EDGES + 255) / 256, 256, 0, stream>>>(ei, woff, rank, sndp);
  k_geom<<<(N_EDGES + 255) / 256, 256, 0, stream>>>(pos, shifts, ei, rank, Yp, radp);
  int prepTot = L_LAY * 65536 + 3 * L_LAY * 4096 + L_LAY * 40960;
  k_prep<<<(prepTot + 255) / 256, 256, 0, stream>>>(w3, w2, Wmix, Wup, Wskip, W3T, w2T, WmixF,
                                                    WupF, WskT);

  const float* fOld = fA;
  float* fNew = fB;
  const u16* fBOld = fBa;
  u16* fBNew = fBb;
  for (int l = 0; l < L_LAY; ++l) {
    k_gather_mega<<<N_NODES / 4, 256, 0, stream>>>(
        radp, Yp, sndp, fBOld, W3T + l * 65536, w2T + l * 4096, WupF + l * 4096,
        w1 + l * NB_R * HID_D, rowptr, nodeOrder, WmixF + l * 4096, fOld, fNew, fBNew,
        WskT + (size_t)l * 40960, Wc + l * NE_EL * 3 * C_CH, Wout + l * C_CH * C_CH,
        Wro + l * C_CH * N_HEADS, species, batch, head, out);
    const float* tf = fNew; fNew = (float*)fOld; fOld = tf;
    const u16* tb = fBNew; fBNew = (u16*)fBOld; fBOld = tb;
  }
}